// Round 13
// baseline (128.853 us; speedup 1.0000x reference)
//
#include <hip/hip_runtime.h>
#include <stdint.h>

#define NAG 4096
#define TOPK 12
#define EPSF 1e-4f
#define NT 512
#define WPB 8               // waves (=agents) per block
#define NBLK (NAG / WPB)    // 512 blocks
#define MTOT (NAG * TOPK)   // 49152 rows

typedef unsigned long long u64;
typedef short short8v __attribute__((ext_vector_type(8)));
typedef float f32x4 __attribute__((ext_vector_type(4)));

// round-to-nearest-even f32 -> bf16 bits
__device__ __forceinline__ unsigned short f2bf(float f) {
    union { float f; unsigned u; } v; v.f = f;
    unsigned r = v.u + 0x7FFFu + ((v.u >> 16) & 1u);
    return (unsigned short)(r >> 16);
}

// One DPP stage of a 64-lane (hi,lo) u64-min reduction (validated R5-R12).
template <int CTRL>
__device__ __forceinline__ void dpp_min_step(unsigned &hi, unsigned &lo) {
    unsigned ohi = (unsigned)__builtin_amdgcn_update_dpp((int)hi, (int)hi, CTRL, 0xf, 0xf, false);
    unsigned olo = (unsigned)__builtin_amdgcn_update_dpp((int)lo, (int)lo, CTRL, 0xf, 0xf, false);
    bool t = (ohi < hi) || (ohi == hi && olo < lo);
    hi = t ? ohi : hi;
    lo = t ? olo : lo;
}

// ======= Kernel 0: preconvert W2,W3 -> bf16 (Wb[0:8192]=W2, Wb[8192:16384]=W3)
__global__ __launch_bounds__(256)
void cbf_prep(const float* __restrict__ W2, const float* __restrict__ W3,
              unsigned short* __restrict__ Wb) {
    int idx = blockIdx.x * 256 + threadIdx.x;          // 64 blocks x 256 = 16384
    float v = (idx < 8192) ? W2[idx] : W3[idx - 8192];
    Wb[idx] = f2bf(v);
}

// ======= Kernel 1: wave-per-agent FUSED select + MFMA MLP =======
// 512 blocks x 512 threads; wave wv owns agent i = blk*8+wv end-to-end.
// R13 change vs R12: per-lane dn bits kept in REGISTERS (dnb[64], fully
// unrolled static indexing) so the survivor-compaction pass is a register
// scan -- no second LDS distance pass. Grid pins occupancy at 4 waves/SIMD,
// so VGPR up to 128 is free under __launch_bounds__(512,4).
__global__ __launch_bounds__(NT, 4)
void cbf_fused(const float* __restrict__ states,
               const float* __restrict__ W1, const float* __restrict__ b1,
               const unsigned short* __restrict__ Wb,   // W2bf | W3bf
               const float* __restrict__ b2, const float* __restrict__ b3,
               const float* __restrict__ W4, const float* __restrict__ b4,
               float* __restrict__ out)
{
    const int t = threadIdx.x;
    const int lane = t & 63;
    const int wv = t >> 6;
    const int i = blockIdx.x * WPB + wv;    // agent

    __shared__ float2 s_xy[NAG];                              // 32 KB
    __shared__ u64 s_surv[WPB][64];                           // 4 KB
    __shared__ int s_sel[WPB][TOPK];
    __shared__ float s_x[WPB][72];                            // flat72 per agent
    __shared__ float s_mask[WPB][TOPK];
    __shared__ __align__(16) unsigned char s_h2[WPB][4096];   // 32 KB

    // ---- Stage: xy -> LDS (coalesced float4 reads, discard zw)
#pragma unroll
    for (int u = 0; u < 8; ++u) {
        int r = u * NT + t;
        float4 sr = reinterpret_cast<const float4*>(states)[r];
        s_xy[r] = make_float2(sr.x, sr.y);
    }
    __syncthreads();   // the ONLY block barrier

    const float2 sif = s_xy[i];   // exact copy of states[i][0..1]
    const float si0 = sif.x, si1 = sif.y;

    // ---- Pass A: 64 candidates/lane; dn bits kept in registers (bit-exact f32)
    unsigned dnb[64];
    unsigned minb = 0xFFFFFFFFu;
    int minj = 0;
#pragma unroll
    for (int u = 0; u < 64; ++u) {
        float2 sj = s_xy[u * 64 + lane];
        float dx0 = __fsub_rn(si0, sj.x);
        float dx1 = __fsub_rn(si1, sj.y);
        float d2 = __fadd_rn(__fadd_rn(__fmul_rn(dx0, dx0), EPSF),
                             __fadd_rn(__fmul_rn(dx1, dx1), EPSF));
        unsigned b = __float_as_uint(__fsqrt_rn(d2));  // positive: bit order == value order
        dnb[u] = b;
        if (b < minb) { minb = b; minj = u * 64 + lane; }  // strict <: lowest j on tie
    }

    // ---- T-find: 12th-smallest lane-min key via 12 static DPP rounds
    unsigned Tb;
    {
        unsigned khi = minb, klo = (unsigned)minj;
        unsigned Tcur = 0;
        for (int r = 0; r < TOPK; ++r) {
            unsigned hi = khi, lo = klo;
            dpp_min_step<0xB1>(hi, lo);    // quad_perm xor1
            dpp_min_step<0x4E>(hi, lo);    // quad_perm xor2
            dpp_min_step<0x124>(hi, lo);   // row_ror:4
            dpp_min_step<0x128>(hi, lo);   // row_ror:8
            dpp_min_step<0x142>(hi, lo);   // row_bcast15
            dpp_min_step<0x143>(hi, lo);   // row_bcast31
            unsigned hw = (unsigned)__builtin_amdgcn_readlane((int)hi, 63);
            unsigned lw = (unsigned)__builtin_amdgcn_readlane((int)lo, 63);
            Tcur = hw;
            if (khi == hw && klo == lw) khi = 0xFFFFFFFFu;   // mask unique winner
        }
        Tb = Tcur;
    }

    // ---- Pass B: REGISTER scan + ballot-compact survivors (dn <= T); >=12 guaranteed
    int cnt = 0;
#pragma unroll
    for (int u = 0; u < 64; ++u) {
        bool p = (dnb[u] <= Tb);
        u64 mk = __ballot(p);
        if (p) {
            int pos = cnt + __popcll(mk & ((1ull << lane) - 1ull));
            if (pos < 64)
                s_surv[wv][pos] = ((u64)dnb[u] << 32) | (unsigned)(u * 64 + lane);
        }
        cnt += __popcll(mk);
    }
    if (cnt > 64) cnt = 64;
    __asm volatile("s_waitcnt lgkmcnt(0)" ::: "memory");
    __builtin_amdgcn_wave_barrier();

    // ---- Rank-select (key order == lax.top_k order)
    if (lane < cnt) {
        u64 kA = s_surv[wv][lane];
        int rA = 0;
        for (int q = 0; q < cnt; ++q)
            rA += (s_surv[wv][q] < kA) ? 1 : 0;     // uniform addr -> broadcast
        if (rA < TOPK) s_sel[wv][rA] = (int)(unsigned)(kA & 0xffffffffull);
    }
    __asm volatile("s_waitcnt lgkmcnt(0)" ::: "memory");
    __builtin_amdgcn_wave_barrier();

    // ---- flat72 + mask
    if (lane < TOPK) {
        int j = s_sel[wv][lane];
        const float4 sj = reinterpret_cast<const float4*>(states)[j];
        const float4 si = reinterpret_cast<const float4*>(states)[i];
        float dx0 = __fsub_rn(si.x, sj.x);
        float dx1 = __fsub_rn(si.y, sj.y);
        float dx2 = __fsub_rn(si.z, sj.z);
        float dx3 = __fsub_rn(si.w, sj.w);
        float d2 = __fadd_rn(__fadd_rn(__fmul_rn(dx0, dx0), EPSF),
                             __fadd_rn(__fmul_rn(dx1, dx1), EPSF));
        float dn = __fsqrt_rn(d2);
        s_x[wv][lane * 6 + 0] = dx0;
        s_x[wv][lane * 6 + 1] = dx1;
        s_x[wv][lane * 6 + 2] = dx2;
        s_x[wv][lane * 6 + 3] = dx3;
        s_x[wv][lane * 6 + 4] = (j == i) ? 1.0f : 0.0f;
        s_x[wv][lane * 6 + 5] = __fsub_rn(dn, 0.8f);
        float mk = (dn <= 1.0f) ? 1.0f : 0.0f;
        s_mask[wv][lane] = mk;
        out[MTOT + i * TOPK + lane] = mk;
    }
    __asm volatile("s_waitcnt lgkmcnt(0)" ::: "memory");
    __builtin_amdgcn_wave_barrier();

    // ---- MLP (per wave; 16-row tile, rows 12..15 zeroed) ----
    const int r16 = lane & 15;      // M row (L1/A) / D col (B) index
    const int hi = lane >> 4;       // 0..3

    // L1 (f32): scrambled input xc[ch] = flat72[ch*12 + r16].
    // A-frag in REGISTERS: lane (r16,hi) computes h1[r16][o] for
    // o = 8hi+e (a0[e], k=0..31) and o = 32+8hi+e (a1[e], k=32..63).
    float xc[6];
#pragma unroll
    for (int ch = 0; ch < 6; ++ch)
        xc[ch] = (r16 < TOPK) ? s_x[wv][ch * TOPK + r16] : 0.0f;

    short8v a0, a1;
#pragma unroll
    for (int e = 0; e < 8; ++e) {
        {
            int o = 8 * hi + e;
            const float2* wr = reinterpret_cast<const float2*>(W1 + o * 6);
            float2 w0 = wr[0], w1 = wr[1], w2 = wr[2];
            float acc = b1[o];
            acc = fmaf(w0.x, xc[0], acc);
            acc = fmaf(w0.y, xc[1], acc);
            acc = fmaf(w1.x, xc[2], acc);
            acc = fmaf(w1.y, xc[3], acc);
            acc = fmaf(w2.x, xc[4], acc);
            acc = fmaf(w2.y, xc[5], acc);
            a0[e] = (r16 < TOPK) ? (short)f2bf(fmaxf(acc, 0.0f)) : (short)0;
        }
        {
            int o = 32 + 8 * hi + e;
            const float2* wr = reinterpret_cast<const float2*>(W1 + o * 6);
            float2 w0 = wr[0], w1 = wr[1], w2 = wr[2];
            float acc = b1[o];
            acc = fmaf(w0.x, xc[0], acc);
            acc = fmaf(w0.y, xc[1], acc);
            acc = fmaf(w1.x, xc[2], acc);
            acc = fmaf(w1.y, xc[3], acc);
            acc = fmaf(w2.x, xc[4], acc);
            acc = fmaf(w2.y, xc[5], acc);
            a1[e] = (r16 < TOPK) ? (short)f2bf(fmaxf(acc, 0.0f)) : (short)0;
        }
    }

    unsigned char* lp2 = s_h2[wv];
    const int c = r16;   // D/B column within tile

    // L2 (MFMA): h2 = relu(h1 @ W2^T + b2), 128 cols; W2bf = Wb[0:8192]
#pragma unroll
    for (int nt = 0; nt < 8; ++nt) {
        int o = nt * 16 + c;
        short8v bf0 = *(const short8v*)(Wb + o * 64 + 8 * hi);
        short8v bf1 = *(const short8v*)(Wb + o * 64 + 32 + 8 * hi);
        float bb = b2[o];
        f32x4 acc = {bb, bb, bb, bb};
        acc = __builtin_amdgcn_mfma_f32_16x16x32_bf16(a0, bf0, acc, 0, 0, 0);
        acc = __builtin_amdgcn_mfma_f32_16x16x32_bf16(a1, bf1, acc, 0, 0, 0);
#pragma unroll
        for (int e = 0; e < 4; ++e) {
            unsigned short hv = f2bf(fmaxf(acc[e], 0.0f));
            int mr = 4 * hi + e;                    // D row
            int slot = (2 * nt + (c >> 3)) ^ (mr & 15);
            *(unsigned short*)(lp2 + mr * 256 + slot * 16 + ((2 * c) & 15)) = hv;
        }
    }
    __asm volatile("s_waitcnt lgkmcnt(0)" ::: "memory");
    __builtin_amdgcn_wave_barrier();

    // L3 (MFMA): h3 = relu(h2 @ W3^T + b3), 64 cols; W3bf = Wb[8192:]
    short8v a3[4];
#pragma unroll
    for (int ks = 0; ks < 4; ++ks)
        a3[ks] = *(short8v*)(lp2 + r16 * 256 + (((4 * ks + hi) ^ r16) * 16));
    float h3r[4][4];
#pragma unroll
    for (int nt = 0; nt < 4; ++nt) {
        int o = nt * 16 + c;
        float bb = b3[o];
        f32x4 ac = {bb, bb, bb, bb};
#pragma unroll
        for (int ks = 0; ks < 4; ++ks) {
            short8v bf = *(const short8v*)(Wb + 8192 + o * 128 + ks * 32 + 8 * hi);
            ac = __builtin_amdgcn_mfma_f32_16x16x32_bf16(a3[ks], bf, ac, 0, 0, 0);
        }
#pragma unroll
        for (int e = 0; e < 4; ++e) h3r[nt][e] = fmaxf(ac[e], 0.0f);
    }

    // L4 (f32): out[m] = (h3 . W4 + b4) * mask; reduce over the 16 c-lanes
    float w4c[4];
#pragma unroll
    for (int nt = 0; nt < 4; ++nt) w4c[nt] = W4[nt * 16 + c];
    float part[4];
#pragma unroll
    for (int e = 0; e < 4; ++e) {
        float p = h3r[0][e] * w4c[0];
        p = fmaf(h3r[1][e], w4c[1], p);
        p = fmaf(h3r[2][e], w4c[2], p);
        p = fmaf(h3r[3][e], w4c[3], p);
        part[e] = p;
    }
#pragma unroll
    for (int off = 1; off <= 8; off <<= 1) {
#pragma unroll
        for (int e = 0; e < 4; ++e)
            part[e] += __shfl_xor(part[e], off, 64);
    }
    if (c == 0) {
        float bb4 = b4[0];
#pragma unroll
        for (int e = 0; e < 4; ++e) {
            int mr = 4 * hi + e;
            if (mr < TOPK)
                out[i * TOPK + mr] = (part[e] + bb4) * s_mask[wv][mr];
        }
    }
}

extern "C" void kernel_launch(void* const* d_in, const int* in_sizes, int n_in,
                              void* d_out, int out_size, void* d_ws, size_t ws_size,
                              hipStream_t stream) {
    const float* states = (const float*)d_in[0];
    const float* W1 = (const float*)d_in[1];
    const float* b1 = (const float*)d_in[2];
    const float* W2 = (const float*)d_in[3];
    const float* b2 = (const float*)d_in[4];
    const float* W3 = (const float*)d_in[5];
    const float* b3 = (const float*)d_in[6];
    const float* W4 = (const float*)d_in[7];
    const float* b4 = (const float*)d_in[8];
    float* out = (float*)d_out;
    unsigned short* Wb = (unsigned short*)d_ws;   // 16384 bf16 = 32 KB

    cbf_prep<<<dim3(64), dim3(256), 0, stream>>>(W2, W3, Wb);
    cbf_fused<<<dim3(NBLK), dim3(NT), 0, stream>>>(states, W1, b1, Wb,
                                                   b2, b3, W4, b4, out);
}

// Round 14
// 114.144 us; speedup vs baseline: 1.1289x; 1.1289x over previous
//
#include <hip/hip_runtime.h>
#include <stdint.h>

#define NAG 4096
#define TOPK 12
#define EPSF 1e-4f
#define NT 1024
#define APB 8               // agents per block (2 waves each)
#define NBLK (NAG / APB)    // 512 blocks
#define MTOT (NAG * TOPK)   // 49152 rows

typedef unsigned long long u64;
typedef short short8v __attribute__((ext_vector_type(8)));
typedef float f32x4 __attribute__((ext_vector_type(4)));

// round-to-nearest-even f32 -> bf16 bits
__device__ __forceinline__ unsigned short f2bf(float f) {
    union { float f; unsigned u; } v; v.f = f;
    unsigned r = v.u + 0x7FFFu + ((v.u >> 16) & 1u);
    return (unsigned short)(r >> 16);
}

// One DPP stage of a 64-lane (hi,lo) u64-min reduction (validated R5-R12).
template <int CTRL>
__device__ __forceinline__ void dpp_min_step(unsigned &hi, unsigned &lo) {
    unsigned ohi = (unsigned)__builtin_amdgcn_update_dpp((int)hi, (int)hi, CTRL, 0xf, 0xf, false);
    unsigned olo = (unsigned)__builtin_amdgcn_update_dpp((int)lo, (int)lo, CTRL, 0xf, 0xf, false);
    bool t = (ohi < hi) || (ohi == hi && olo < lo);
    hi = t ? ohi : hi;
    lo = t ? olo : lo;
}

// ======= Kernel 0: preconvert W2,W3 -> bf16 (Wb[0:8192]=W2, Wb[8192:16384]=W3)
__global__ __launch_bounds__(256)
void cbf_prep(const float* __restrict__ W2, const float* __restrict__ W3,
              unsigned short* __restrict__ Wb) {
    int idx = blockIdx.x * 256 + threadIdx.x;          // 64 blocks x 256 = 16384
    float v = (idx < 8192) ? W2[idx] : W3[idx - 8192];
    Wb[idx] = f2bf(v);
}

// ======= Kernel 1: 2-waves-per-agent FUSED select + MFMA MLP =======
// 512 blocks x 1024 threads: 8 agents/block, 2 waves/agent -> 8192 waves
// (8/SIMD structural occupancy, vs 4 at 1 wave/agent). VGPR must stay <=64
// (launch_bounds 1024,8); selection keeps NO dn array in registers (R13's
// dnb[64] spilled: 92MB scratch writes) -- pass B recomputes from LDS.
__global__ __launch_bounds__(NT, 8)
void cbf_fused(const float* __restrict__ states,
               const float* __restrict__ W1, const float* __restrict__ b1,
               const unsigned short* __restrict__ Wb,   // W2bf | W3bf
               const float* __restrict__ b2, const float* __restrict__ b3,
               const float* __restrict__ W4, const float* __restrict__ b4,
               float* __restrict__ out)
{
    const int t = threadIdx.x;
    const int lane = t & 63;
    const int wv = t >> 6;          // 0..15
    const int a = wv >> 1;          // agent slot 0..7
    const int p = wv & 1;           // phase wave 0/1
    const int i = blockIdx.x * APB + a;

    __shared__ float2 s_xy[NAG];                              // 32 KB
    __shared__ u64 s_lmin[APB][128];                          // 8 KB
    __shared__ u64 s_surv[APB][64];                           // 4 KB
    __shared__ int s_sel[APB][TOPK];
    __shared__ float s_x[APB][72];
    __shared__ float s_mask[APB][TOPK];
    __shared__ unsigned s_cnt[APB];
    __shared__ unsigned s_T[APB];
    __shared__ __align__(16) unsigned char s_h2[APB][2048];   // 16 KB (half-chunked)

    if (t < APB) s_cnt[t] = 0;

    // ---- Stage: xy -> LDS (coalesced float4 reads, discard zw)
#pragma unroll
    for (int u = 0; u < 4; ++u) {
        int r = u * NT + t;
        float4 sr = reinterpret_cast<const float4*>(states)[r];
        s_xy[r] = make_float2(sr.x, sr.y);
    }
    __syncthreads();   // #1

    const float2 sif = s_xy[i];
    const float si0 = sif.x, si1 = sif.y;

    // ---- Pass A: this wave's 32 candidate groups (bit-exact f32)
    unsigned minb = 0xFFFFFFFFu;
    int minj = 0;
#pragma unroll 8
    for (int u = 0; u < 32; ++u) {
        int j = (p * 32 + u) * 64 + lane;
        float2 sj = s_xy[j];
        float dx0 = __fsub_rn(si0, sj.x);
        float dx1 = __fsub_rn(si1, sj.y);
        float d2 = __fadd_rn(__fadd_rn(__fmul_rn(dx0, dx0), EPSF),
                             __fadd_rn(__fmul_rn(dx1, dx1), EPSF));
        unsigned b = __float_as_uint(__fsqrt_rn(d2));  // positive: bit order == value order
        if (b < minb) { minb = b; minj = j; }          // strict <: lowest j on tie
    }
    s_lmin[a][p * 64 + lane] = ((u64)minb << 32) | (unsigned)minj;
    __syncthreads();   // #2

    // ---- T-find (wave p=0): 12th-smallest of 128 lane-min keys.
    // T >= true d12 (group-mins are a subset of all dn -> their 12th smallest
    // >= overall 12th smallest) and >=12 candidates <= T (the 12 winners).
    if (p == 0) {
        unsigned khi[2], klo[2];
#pragma unroll
        for (int q = 0; q < 2; ++q) {
            u64 kk = s_lmin[a][lane + q * 64];
            klo[q] = (unsigned)(kk & 0xffffffffull);
            khi[q] = (unsigned)(kk >> 32);
        }
        unsigned Tb = 0;
        for (int r = 0; r < TOPK; ++r) {
            unsigned hi = khi[0], lo = klo[0];
            {
                bool tk = (khi[1] < hi) || (khi[1] == hi && klo[1] < lo);
                hi = tk ? khi[1] : hi;
                lo = tk ? klo[1] : lo;
            }
            dpp_min_step<0xB1>(hi, lo);    // quad_perm xor1
            dpp_min_step<0x4E>(hi, lo);    // quad_perm xor2
            dpp_min_step<0x124>(hi, lo);   // row_ror:4
            dpp_min_step<0x128>(hi, lo);   // row_ror:8
            dpp_min_step<0x142>(hi, lo);   // row_bcast15
            dpp_min_step<0x143>(hi, lo);   // row_bcast31
            unsigned hw = (unsigned)__builtin_amdgcn_readlane((int)hi, 63);
            unsigned lw = (unsigned)__builtin_amdgcn_readlane((int)lo, 63);
            Tb = hw;
#pragma unroll
            for (int q = 0; q < 2; ++q) {
                bool w = (khi[q] == hw) && (klo[q] == lw);
                khi[q] = w ? 0xFFFFFFFFu : khi[q];     // mask unique winner
            }
        }
        if (lane == 0) s_T[a] = Tb;
    }
    __syncthreads();   // #3

    // ---- Pass B: recompute + ballot-compact survivors (dn <= T), both waves.
    // Survivor ORDER is irrelevant (rank-select is order-free); per-agent
    // base via rare LDS atomic (most iterations have zero survivors).
    {
        unsigned Tb = s_T[a];
#pragma unroll 8
        for (int u = 0; u < 32; ++u) {
            int j = (p * 32 + u) * 64 + lane;
            float2 sj = s_xy[j];
            float dx0 = __fsub_rn(si0, sj.x);
            float dx1 = __fsub_rn(si1, sj.y);
            float d2 = __fadd_rn(__fadd_rn(__fmul_rn(dx0, dx0), EPSF),
                                 __fadd_rn(__fmul_rn(dx1, dx1), EPSF));
            unsigned b = __float_as_uint(__fsqrt_rn(d2));
            bool pr = (b <= Tb);
            u64 mk = __ballot(pr);
            if (mk != 0ull) {
                unsigned nsel = (unsigned)__popcll(mk);
                unsigned base = 0;
                if (lane == 0) base = atomicAdd(&s_cnt[a], nsel);
                base = (unsigned)__builtin_amdgcn_readfirstlane((int)base);
                if (pr) {
                    int pos = (int)base + __popcll(mk & ((1ull << lane) - 1ull));
                    if (pos < 64)
                        s_surv[a][pos] = ((u64)b << 32) | (unsigned)j;
                }
            }
        }
    }
    __syncthreads();   // #4 (last block barrier)

    if (p != 0) return;   // phase-1 waves done

    // ---- Rank-select (key order == lax.top_k order)
    {
        int cnt = (int)s_cnt[a];
        if (cnt > 64) cnt = 64;
        if (lane < cnt) {
            u64 kA = s_surv[a][lane];
            int rA = 0;
            for (int q = 0; q < cnt; ++q)
                rA += (s_surv[a][q] < kA) ? 1 : 0;     // uniform addr -> broadcast
            if (rA < TOPK) s_sel[a][rA] = (int)(unsigned)(kA & 0xffffffffull);
        }
    }
    __asm volatile("s_waitcnt lgkmcnt(0)" ::: "memory");
    __builtin_amdgcn_wave_barrier();

    // ---- flat72 + mask
    if (lane < TOPK) {
        int j = s_sel[a][lane];
        const float4 sj = reinterpret_cast<const float4*>(states)[j];
        const float4 si = reinterpret_cast<const float4*>(states)[i];
        float dx0 = __fsub_rn(si.x, sj.x);
        float dx1 = __fsub_rn(si.y, sj.y);
        float dx2 = __fsub_rn(si.z, sj.z);
        float dx3 = __fsub_rn(si.w, sj.w);
        float d2 = __fadd_rn(__fadd_rn(__fmul_rn(dx0, dx0), EPSF),
                             __fadd_rn(__fmul_rn(dx1, dx1), EPSF));
        float dn = __fsqrt_rn(d2);
        s_x[a][lane * 6 + 0] = dx0;
        s_x[a][lane * 6 + 1] = dx1;
        s_x[a][lane * 6 + 2] = dx2;
        s_x[a][lane * 6 + 3] = dx3;
        s_x[a][lane * 6 + 4] = (j == i) ? 1.0f : 0.0f;
        s_x[a][lane * 6 + 5] = __fsub_rn(dn, 0.8f);
        float mk = (dn <= 1.0f) ? 1.0f : 0.0f;
        s_mask[a][lane] = mk;
        out[MTOT + i * TOPK + lane] = mk;
    }
    __asm volatile("s_waitcnt lgkmcnt(0)" ::: "memory");
    __builtin_amdgcn_wave_barrier();

    // ---- MLP (wave p=0; 16-row tile, rows 12..15 zeroed) ----
    const int r16 = lane & 15;      // M row (L1/A) / D col (B) index
    const int hi = lane >> 4;       // 0..3
    const int c = r16;

    // L1 (f32): scrambled input xc[ch] = flat72[ch*12 + r16]; A-frags in regs.
    float xc[6];
#pragma unroll
    for (int ch = 0; ch < 6; ++ch)
        xc[ch] = (r16 < TOPK) ? s_x[a][ch * TOPK + r16] : 0.0f;

    short8v a0, a1;
#pragma unroll
    for (int e = 0; e < 8; ++e) {
        {
            int o = 8 * hi + e;
            const float2* wr = reinterpret_cast<const float2*>(W1 + o * 6);
            float2 w0 = wr[0], w1 = wr[1], w2 = wr[2];
            float acc = b1[o];
            acc = fmaf(w0.x, xc[0], acc);
            acc = fmaf(w0.y, xc[1], acc);
            acc = fmaf(w1.x, xc[2], acc);
            acc = fmaf(w1.y, xc[3], acc);
            acc = fmaf(w2.x, xc[4], acc);
            acc = fmaf(w2.y, xc[5], acc);
            a0[e] = (r16 < TOPK) ? (short)f2bf(fmaxf(acc, 0.0f)) : (short)0;
        }
        {
            int o = 32 + 8 * hi + e;
            const float2* wr = reinterpret_cast<const float2*>(W1 + o * 6);
            float2 w0 = wr[0], w1 = wr[1], w2 = wr[2];
            float acc = b1[o];
            acc = fmaf(w0.x, xc[0], acc);
            acc = fmaf(w0.y, xc[1], acc);
            acc = fmaf(w1.x, xc[2], acc);
            acc = fmaf(w1.y, xc[3], acc);
            acc = fmaf(w2.x, xc[4], acc);
            acc = fmaf(w2.y, xc[5], acc);
            a1[e] = (r16 < TOPK) ? (short)f2bf(fmaxf(acc, 0.0f)) : (short)0;
        }
    }

    unsigned char* lp2 = s_h2[a];

    // L3 accumulators (b3 preloaded); L2/L3 interleaved in 2 half-chunks of h2
    // (2 KB buffer; write slot ^(mr&7), read slot ^(r16&7) -- same-row masks
    // match, so unswizzled slot correspondence 2*ntl+(c>>3) <-> 4*ksl+hi holds
    // exactly as in the validated full-width version).
    f32x4 ac3[4];
#pragma unroll
    for (int nt = 0; nt < 4; ++nt) {
        float bb = b3[nt * 16 + c];
        ac3[nt] = (f32x4){bb, bb, bb, bb};
    }

#pragma unroll
    for (int half = 0; half < 2; ++half) {
        // L2 half: output cols o = (half*4+ntl)*16 + c
#pragma unroll
        for (int ntl = 0; ntl < 4; ++ntl) {
            int nt = half * 4 + ntl;
            int o = nt * 16 + c;
            short8v bf0 = *(const short8v*)(Wb + o * 64 + 8 * hi);
            short8v bf1 = *(const short8v*)(Wb + o * 64 + 32 + 8 * hi);
            float bb = b2[o];
            f32x4 acc = {bb, bb, bb, bb};
            acc = __builtin_amdgcn_mfma_f32_16x16x32_bf16(a0, bf0, acc, 0, 0, 0);
            acc = __builtin_amdgcn_mfma_f32_16x16x32_bf16(a1, bf1, acc, 0, 0, 0);
#pragma unroll
            for (int e = 0; e < 4; ++e) {
                unsigned short hv = f2bf(fmaxf(acc[e], 0.0f));
                int mr = 4 * hi + e;                        // D row
                int slot = (2 * ntl + (c >> 3)) ^ (mr & 7);
                *(unsigned short*)(lp2 + mr * 128 + slot * 16 + ((2 * c) & 15)) = hv;
            }
        }
        __asm volatile("s_waitcnt lgkmcnt(0)" ::: "memory");
        __builtin_amdgcn_wave_barrier();

        // L3 partial: global ks = half*2 + ksl
#pragma unroll
        for (int ksl = 0; ksl < 2; ++ksl) {
            short8v a3 = *(short8v*)(lp2 + r16 * 128 + (((4 * ksl + hi) ^ (r16 & 7)) * 16));
            int ks = half * 2 + ksl;
#pragma unroll
            for (int nt = 0; nt < 4; ++nt) {
                int o = nt * 16 + c;
                short8v bf = *(const short8v*)(Wb + 8192 + o * 128 + ks * 32 + 8 * hi);
                ac3[nt] = __builtin_amdgcn_mfma_f32_16x16x32_bf16(a3, bf, ac3[nt], 0, 0, 0);
            }
        }
        if (half == 0) {   // drain reads before half-1 overwrites the buffer
            __asm volatile("s_waitcnt lgkmcnt(0)" ::: "memory");
            __builtin_amdgcn_wave_barrier();
        }
    }

    float h3r[4][4];
#pragma unroll
    for (int nt = 0; nt < 4; ++nt)
#pragma unroll
        for (int e = 0; e < 4; ++e) h3r[nt][e] = fmaxf(ac3[nt][e], 0.0f);

    // L4 (f32): out[m] = (h3 . W4 + b4) * mask; reduce over the 16 c-lanes
    float w4c[4];
#pragma unroll
    for (int nt = 0; nt < 4; ++nt) w4c[nt] = W4[nt * 16 + c];
    float part[4];
#pragma unroll
    for (int e = 0; e < 4; ++e) {
        float pp = h3r[0][e] * w4c[0];
        pp = fmaf(h3r[1][e], w4c[1], pp);
        pp = fmaf(h3r[2][e], w4c[2], pp);
        pp = fmaf(h3r[3][e], w4c[3], pp);
        part[e] = pp;
    }
#pragma unroll
    for (int off = 1; off <= 8; off <<= 1) {
#pragma unroll
        for (int e = 0; e < 4; ++e)
            part[e] += __shfl_xor(part[e], off, 64);
    }
    if (c == 0) {
        float bb4 = b4[0];
#pragma unroll
        for (int e = 0; e < 4; ++e) {
            int mr = 4 * hi + e;
            if (mr < TOPK)
                out[i * TOPK + mr] = (part[e] + bb4) * s_mask[a][mr];
        }
    }
}

extern "C" void kernel_launch(void* const* d_in, const int* in_sizes, int n_in,
                              void* d_out, int out_size, void* d_ws, size_t ws_size,
                              hipStream_t stream) {
    const float* states = (const float*)d_in[0];
    const float* W1 = (const float*)d_in[1];
    const float* b1 = (const float*)d_in[2];
    const float* W2 = (const float*)d_in[3];
    const float* b2 = (const float*)d_in[4];
    const float* W3 = (const float*)d_in[5];
    const float* b3 = (const float*)d_in[6];
    const float* W4 = (const float*)d_in[7];
    const float* b4 = (const float*)d_in[8];
    float* out = (float*)d_out;
    unsigned short* Wb = (unsigned short*)d_ws;   // 16384 bf16 = 32 KB

    cbf_prep<<<dim3(64), dim3(256), 0, stream>>>(W2, W3, Wb);
    cbf_fused<<<dim3(NBLK), dim3(NT), 0, stream>>>(states, W1, b1, Wb,
                                                   b2, b3, W4, b4, out);
}

// Round 16
// 100.682 us; speedup vs baseline: 1.2798x; 1.1337x over previous
//
#include <hip/hip_runtime.h>
#include <stdint.h>

#define NAG 4096
#define TOPK 12
#define EPSF 1e-4f
#define NT 512
#define WPB 8               // waves (=agents) per block
#define NBLK (NAG / WPB)    // 512 blocks
#define MTOT (NAG * TOPK)   // 49152 rows

typedef unsigned long long u64;
typedef short short8v __attribute__((ext_vector_type(8)));
typedef float f32x4 __attribute__((ext_vector_type(4)));

// round-to-nearest-even f32 -> bf16 bits
__device__ __forceinline__ unsigned short f2bf(float f) {
    union { float f; unsigned u; } v; v.f = f;
    unsigned r = v.u + 0x7FFFu + ((v.u >> 16) & 1u);
    return (unsigned short)(r >> 16);
}

// One DPP stage of a 64-lane (hi,lo) u64-min reduction (validated R5-R12).
template <int CTRL>
__device__ __forceinline__ void dpp_min_step(unsigned &hi, unsigned &lo) {
    unsigned ohi = (unsigned)__builtin_amdgcn_update_dpp((int)hi, (int)hi, CTRL, 0xf, 0xf, false);
    unsigned olo = (unsigned)__builtin_amdgcn_update_dpp((int)lo, (int)lo, CTRL, 0xf, 0xf, false);
    bool t = (ohi < hi) || (ohi == hi && olo < lo);
    hi = t ? ohi : hi;
    lo = t ? olo : lo;
}

// ======= Kernel 0: preconvert W2,W3 -> bf16 (Wb[0:8192]=W2, Wb[8192:16384]=W3)
__global__ __launch_bounds__(256)
void cbf_prep(const float* __restrict__ W2, const float* __restrict__ W3,
              unsigned short* __restrict__ Wb) {
    int idx = blockIdx.x * 256 + threadIdx.x;          // 64 blocks x 256 = 16384
    float v = (idx < 8192) ? W2[idx] : W3[idx - 8192];
    Wb[idx] = f2bf(v);
}

// ======= Kernel 1: wave-per-agent FUSED select + MFMA MLP (R12 structure) ====
// R15 vs R12 (43.6us): (a) paired ds_read_b128 in both distance passes
// (32 LDS ops instead of 64); (b) hot passes rank on d^2 bits (no sqrt);
// threshold inflated +16 ulp (provably covers true top-12); survivors get
// exact (dn,j) keys before rank-select. MLP verbatim from R12.
__global__ __launch_bounds__(NT, 4)
void cbf_fused(const float* __restrict__ states,
               const float* __restrict__ W1, const float* __restrict__ b1,
               const unsigned short* __restrict__ Wb,   // W2bf | W3bf
               const float* __restrict__ b2, const float* __restrict__ b3,
               const float* __restrict__ W4, const float* __restrict__ b4,
               float* __restrict__ out)
{
    const int t = threadIdx.x;
    const int lane = t & 63;
    const int wv = t >> 6;
    const int i = blockIdx.x * WPB + wv;    // agent

    __shared__ __align__(16) float2 s_xy[NAG];                // 32 KB
    __shared__ u64 s_surv[WPB][64];                           // 4 KB
    __shared__ int s_sel[WPB][TOPK];
    __shared__ float s_x[WPB][72];                            // flat72 per agent
    __shared__ float s_mask[WPB][TOPK];
    __shared__ __align__(16) unsigned char s_h2[WPB][4096];   // 32 KB

    // ---- Stage: xy -> LDS (coalesced float4 reads, discard zw)
#pragma unroll
    for (int u = 0; u < 8; ++u) {
        int r = u * NT + t;
        float4 sr = reinterpret_cast<const float4*>(states)[r];
        s_xy[r] = make_float2(sr.x, sr.y);
    }
    __syncthreads();   // the ONLY block barrier

    const float2 sif = s_xy[i];
    const float si0 = sif.x, si1 = sif.y;

    // ---- Pass A: 64 candidates/lane via 32 paired b128 reads; d^2 keys
    // (d2 > 0 so bit order == value order; numpy rounding: mul,add,add separate)
    unsigned minb = 0xFFFFFFFFu;
    int minj = 0;
#pragma unroll 8
    for (int u = 0; u < 32; ++u) {
        int jp = u * 128 + 2 * lane;
        float4 s2 = *reinterpret_cast<const float4*>(&s_xy[jp]);
        float a0 = __fsub_rn(si0, s2.x);
        float a1 = __fsub_rn(si1, s2.y);
        unsigned b0 = __float_as_uint(
            __fadd_rn(__fadd_rn(__fmul_rn(a0, a0), EPSF),
                      __fadd_rn(__fmul_rn(a1, a1), EPSF)));
        float c0 = __fsub_rn(si0, s2.z);
        float c1 = __fsub_rn(si1, s2.w);
        unsigned b1v = __float_as_uint(
            __fadd_rn(__fadd_rn(__fmul_rn(c0, c0), EPSF),
                      __fadd_rn(__fmul_rn(c1, c1), EPSF)));
        if (b0 < minb) { minb = b0; minj = jp; }        // ascending j: strict <
        if (b1v < minb) { minb = b1v; minj = jp + 1; }
    }

    // ---- T-find: 12th-smallest lane-min d^2 key via 12 static DPP rounds
    unsigned Tb;
    {
        unsigned khi = minb, klo = (unsigned)minj;
        unsigned Tcur = 0;
        for (int r = 0; r < TOPK; ++r) {
            unsigned hi = khi, lo = klo;
            dpp_min_step<0xB1>(hi, lo);    // quad_perm xor1
            dpp_min_step<0x4E>(hi, lo);    // quad_perm xor2
            dpp_min_step<0x124>(hi, lo);   // row_ror:4
            dpp_min_step<0x128>(hi, lo);   // row_ror:8
            dpp_min_step<0x142>(hi, lo);   // row_bcast15
            dpp_min_step<0x143>(hi, lo);   // row_bcast31
            unsigned hw = (unsigned)__builtin_amdgcn_readlane((int)hi, 63);
            unsigned lw = (unsigned)__builtin_amdgcn_readlane((int)lo, 63);
            Tcur = hw;
            if (khi == hw && klo == lw) khi = 0xFFFFFFFFu;   // mask unique winner
        }
        Tb = Tcur;
    }
    // +16 ulp inflation: covers every x with dn(x) <= dn(Tb) (needs ~2 ulp;
    // 16 for margin). Guarantees survivors >= the true top-12 by (dn,j).
    const unsigned TbP = Tb + 16;

    // ---- Pass B: recompute (paired b128) + ballot-compact survivors d2 <= TbP
    int cnt = 0;
#pragma unroll 8
    for (int u = 0; u < 32; ++u) {
        int jp = u * 128 + 2 * lane;
        float4 s2 = *reinterpret_cast<const float4*>(&s_xy[jp]);
        float a0 = __fsub_rn(si0, s2.x);
        float a1 = __fsub_rn(si1, s2.y);
        unsigned b0 = __float_as_uint(
            __fadd_rn(__fadd_rn(__fmul_rn(a0, a0), EPSF),
                      __fadd_rn(__fmul_rn(a1, a1), EPSF)));
        float c0 = __fsub_rn(si0, s2.z);
        float c1 = __fsub_rn(si1, s2.w);
        unsigned b1v = __float_as_uint(
            __fadd_rn(__fadd_rn(__fmul_rn(c0, c0), EPSF),
                      __fadd_rn(__fmul_rn(c1, c1), EPSF)));
        bool p0 = (b0 <= TbP);
        u64 m0 = __ballot(p0);
        if (p0) {
            int pos = cnt + __popcll(m0 & ((1ull << lane) - 1ull));
            if (pos < 64) s_surv[wv][pos] = ((u64)b0 << 32) | (unsigned)jp;
        }
        cnt += __popcll(m0);
        bool p1 = (b1v <= TbP);
        u64 m1 = __ballot(p1);
        if (p1) {
            int pos = cnt + __popcll(m1 & ((1ull << lane) - 1ull));
            if (pos < 64) s_surv[wv][pos] = ((u64)b1v << 32) | (unsigned)(jp + 1);
        }
        cnt += __popcll(m1);
    }
    if (cnt > 64) cnt = 64;
    __asm volatile("s_waitcnt lgkmcnt(0)" ::: "memory");
    __builtin_amdgcn_wave_barrier();

    // ---- Convert survivor keys to exact (dn_bits, j) -- one sqrt per survivor
    if (lane < cnt) {
        u64 kA = s_surv[wv][lane];
        unsigned j = (unsigned)(kA & 0xffffffffull);
        float dn = __fsqrt_rn(__uint_as_float((unsigned)(kA >> 32)));
        s_surv[wv][lane] = ((u64)__float_as_uint(dn) << 32) | j;
    }
    __asm volatile("s_waitcnt lgkmcnt(0)" ::: "memory");
    __builtin_amdgcn_wave_barrier();

    // ---- Rank-select on exact (dn,j) keys (== lax.top_k order, ties by index)
    if (lane < cnt) {
        u64 kA = s_surv[wv][lane];
        int rA = 0;
        for (int q = 0; q < cnt; ++q)
            rA += (s_surv[wv][q] < kA) ? 1 : 0;     // uniform addr -> broadcast
        if (rA < TOPK) s_sel[wv][rA] = (int)(unsigned)(kA & 0xffffffffull);
    }
    __asm volatile("s_waitcnt lgkmcnt(0)" ::: "memory");
    __builtin_amdgcn_wave_barrier();

    // ---- flat72 + mask (bit-exact recompute from global states)
    if (lane < TOPK) {
        int j = s_sel[wv][lane];
        const float4 sj = reinterpret_cast<const float4*>(states)[j];
        const float4 si = reinterpret_cast<const float4*>(states)[i];
        float dx0 = __fsub_rn(si.x, sj.x);
        float dx1 = __fsub_rn(si.y, sj.y);
        float dx2 = __fsub_rn(si.z, sj.z);
        float dx3 = __fsub_rn(si.w, sj.w);
        float d2 = __fadd_rn(__fadd_rn(__fmul_rn(dx0, dx0), EPSF),
                             __fadd_rn(__fmul_rn(dx1, dx1), EPSF));
        float dn = __fsqrt_rn(d2);
        s_x[wv][lane * 6 + 0] = dx0;
        s_x[wv][lane * 6 + 1] = dx1;
        s_x[wv][lane * 6 + 2] = dx2;
        s_x[wv][lane * 6 + 3] = dx3;
        s_x[wv][lane * 6 + 4] = (j == i) ? 1.0f : 0.0f;
        s_x[wv][lane * 6 + 5] = __fsub_rn(dn, 0.8f);
        float mk = (dn <= 1.0f) ? 1.0f : 0.0f;
        s_mask[wv][lane] = mk;
        out[MTOT + i * TOPK + lane] = mk;
    }
    __asm volatile("s_waitcnt lgkmcnt(0)" ::: "memory");
    __builtin_amdgcn_wave_barrier();

    // ---- MLP (per wave; 16-row tile, rows 12..15 zeroed) -- verbatim R12 ----
    const int r16 = lane & 15;      // M row (L1/A) / D col (B) index
    const int hi = lane >> 4;       // 0..3

    float xc[6];
#pragma unroll
    for (int ch = 0; ch < 6; ++ch)
        xc[ch] = (r16 < TOPK) ? s_x[wv][ch * TOPK + r16] : 0.0f;

    short8v a0, a1;
#pragma unroll
    for (int e = 0; e < 8; ++e) {
        {
            int o = 8 * hi + e;
            const float2* wr = reinterpret_cast<const float2*>(W1 + o * 6);
            float2 w0 = wr[0], w1 = wr[1], w2 = wr[2];
            float acc = b1[o];
            acc = fmaf(w0.x, xc[0], acc);
            acc = fmaf(w0.y, xc[1], acc);
            acc = fmaf(w1.x, xc[2], acc);
            acc = fmaf(w1.y, xc[3], acc);
            acc = fmaf(w2.x, xc[4], acc);
            acc = fmaf(w2.y, xc[5], acc);
            a0[e] = (r16 < TOPK) ? (short)f2bf(fmaxf(acc, 0.0f)) : (short)0;
        }
        {
            int o = 32 + 8 * hi + e;
            const float2* wr = reinterpret_cast<const float2*>(W1 + o * 6);
            float2 w0 = wr[0], w1 = wr[1], w2 = wr[2];
            float acc = b1[o];
            acc = fmaf(w0.x, xc[0], acc);
            acc = fmaf(w0.y, xc[1], acc);
            acc = fmaf(w1.x, xc[2], acc);
            acc = fmaf(w1.y, xc[3], acc);
            acc = fmaf(w2.x, xc[4], acc);
            acc = fmaf(w2.y, xc[5], acc);
            a1[e] = (r16 < TOPK) ? (short)f2bf(fmaxf(acc, 0.0f)) : (short)0;
        }
    }

    unsigned char* lp2 = s_h2[wv];
    const int c = r16;   // D/B column within tile

    // L2 (MFMA): h2 = relu(h1 @ W2^T + b2), 128 cols; W2bf = Wb[0:8192]
#pragma unroll
    for (int nt = 0; nt < 8; ++nt) {
        int o = nt * 16 + c;
        short8v bf0 = *(const short8v*)(Wb + o * 64 + 8 * hi);
        short8v bf1 = *(const short8v*)(Wb + o * 64 + 32 + 8 * hi);
        float bb = b2[o];
        f32x4 acc = {bb, bb, bb, bb};
        acc = __builtin_amdgcn_mfma_f32_16x16x32_bf16(a0, bf0, acc, 0, 0, 0);
        acc = __builtin_amdgcn_mfma_f32_16x16x32_bf16(a1, bf1, acc, 0, 0, 0);
#pragma unroll
        for (int e = 0; e < 4; ++e) {
            unsigned short hv = f2bf(fmaxf(acc[e], 0.0f));
            int mr = 4 * hi + e;                    // D row
            int slot = (2 * nt + (c >> 3)) ^ (mr & 15);
            *(unsigned short*)(lp2 + mr * 256 + slot * 16 + ((2 * c) & 15)) = hv;
        }
    }
    __asm volatile("s_waitcnt lgkmcnt(0)" ::: "memory");
    __builtin_amdgcn_wave_barrier();

    // L3 (MFMA): h3 = relu(h2 @ W3^T + b3), 64 cols; W3bf = Wb[8192:]
    short8v a3[4];
#pragma unroll
    for (int ks = 0; ks < 4; ++ks)
        a3[ks] = *(short8v*)(lp2 + r16 * 256 + (((4 * ks + hi) ^ r16) * 16));
    float h3r[4][4];
#pragma unroll
    for (int nt = 0; nt < 4; ++nt) {
        int o = nt * 16 + c;
        float bb = b3[o];
        f32x4 ac = {bb, bb, bb, bb};
#pragma unroll
        for (int ks = 0; ks < 4; ++ks) {
            short8v bf = *(const short8v*)(Wb + 8192 + o * 128 + ks * 32 + 8 * hi);
            ac = __builtin_amdgcn_mfma_f32_16x16x32_bf16(a3[ks], bf, ac, 0, 0, 0);
        }
#pragma unroll
        for (int e = 0; e < 4; ++e) h3r[nt][e] = fmaxf(ac[e], 0.0f);
    }

    // L4 (f32): out[m] = (h3 . W4 + b4) * mask; reduce over the 16 c-lanes
    float w4c[4];
#pragma unroll
    for (int nt = 0; nt < 4; ++nt) w4c[nt] = W4[nt * 16 + c];
    float part[4];
#pragma unroll
    for (int e = 0; e < 4; ++e) {
        float p = h3r[0][e] * w4c[0];
        p = fmaf(h3r[1][e], w4c[1], p);
        p = fmaf(h3r[2][e], w4c[2], p);
        p = fmaf(h3r[3][e], w4c[3], p);
        part[e] = p;
    }
#pragma unroll
    for (int off = 1; off <= 8; off <<= 1) {
#pragma unroll
        for (int e = 0; e < 4; ++e)
            part[e] += __shfl_xor(part[e], off, 64);
    }
    if (c == 0) {
        float bb4 = b4[0];
#pragma unroll
        for (int e = 0; e < 4; ++e) {
            int mr = 4 * hi + e;
            if (mr < TOPK)
                out[i * TOPK + mr] = (part[e] + bb4) * s_mask[wv][mr];
        }
    }
}

extern "C" void kernel_launch(void* const* d_in, const int* in_sizes, int n_in,
                              void* d_out, int out_size, void* d_ws, size_t ws_size,
                              hipStream_t stream) {
    const float* states = (const float*)d_in[0];
    const float* W1 = (const float*)d_in[1];
    const float* b1 = (const float*)d_in[2];
    const float* W2 = (const float*)d_in[3];
    const float* b2 = (const float*)d_in[4];
    const float* W3 = (const float*)d_in[5];
    const float* b3 = (const float*)d_in[6];
    const float* W4 = (const float*)d_in[7];
    const float* b4 = (const float*)d_in[8];
    float* out = (float*)d_out;
    unsigned short* Wb = (unsigned short*)d_ws;   // 16384 bf16 = 32 KB

    cbf_prep<<<dim3(64), dim3(256), 0, stream>>>(W2, W3, Wb);
    cbf_fused<<<dim3(NBLK), dim3(NT), 0, stream>>>(states, W1, b1, Wb,
                                                   b2, b3, W4, b4, out);
}